// Round 2
// baseline (613.854 us; speedup 1.0000x reference)
//
#include <hip/hip_runtime.h>
#include <hip/hip_bf16.h>

// ---------------------------------------------------------------------------
// Bank attention, fully fused:
//   out = softmax((z@Wq).(tanh(E)@Wk)^T/8) @ (tanh(E)@Wv), scores also output.
// N=65536, D_Q=256, D_MODEL=512, T=128 tokens, H=8 heads, d=64.
// kernel 1 (setup): kb=tanh(E)@Wk [t][c] bf16, vtb=(tanh(E)@Wv)^T [c][t] bf16,
//                   wqt=Wq^T [c][k] bf16.            (~512 KB workspace total)
// kernel 2 (fused): per block: 128 rows x 2 heads.
//   phase 1: q-tile = z(f32->bf16 reg-staged) @ wqt(global_load_lds), MFMA.
//   phase 2: per wave (64 rows x 1 head): q acc -> LDS(swizzled) -> A-frags,
//            QK^T MFMA, wave-parallel softmax, P -> LDS -> PV MFMA.
//   q / qb never touch HBM. Mandatory traffic ~470 MB -> ~75us roofline.
// ---------------------------------------------------------------------------

typedef unsigned short u16;
typedef __attribute__((ext_vector_type(8))) short bf8_t;   // 8 bf16
typedef __attribute__((ext_vector_type(4))) float f4_t;    // MFMA C/D

#define DQ 256
#define DM 512
#define NT 128

__device__ inline u16 f2bf(float f) {   // round-to-nearest-even f32->bf16
    union { float f; unsigned u; } v; v.f = f;
    unsigned r = v.u + 0x7fffu + ((v.u >> 16) & 1u);
    return (u16)(r >> 16);
}

__device__ inline void gload_lds16(const void* g, void* l) {
    __builtin_amdgcn_global_load_lds(
        (const __attribute__((address_space(1))) void*)g,
        (__attribute__((address_space(3))) void*)l, 16, 0, 0);
}

// ---------------------------------------------------------------------------
// setup: blocks 0..127: k/v projections (f32 math, bf16 store).
//          block b: tokens (b>>3)*8..+8 (one per wave), cols (b&7)*64..+64.
//        blocks 128..159: Wq transpose via LDS 64x64 tile -> wqt bf16.
// ---------------------------------------------------------------------------
__global__ __launch_bounds__(512) void setup_kernel(
        const float* __restrict__ embed, const float* __restrict__ Wq,
        const float* __restrict__ Wk, const float* __restrict__ Wv,
        u16* __restrict__ wqt, u16* __restrict__ kb, u16* __restrict__ vtb) {
    const int b = blockIdx.x, t = threadIdx.x;
    if (b < 128) {
        __shared__ float bank[8][DM];
        const int tg = b >> 3, cg = b & 7;
        #pragma unroll
        for (int i = 0; i < 8; ++i)
            bank[i][t] = tanhf(embed[(size_t)(tg * 8 + i) * DM + t]);
        __syncthreads();
        const int tok = t >> 6;                 // wave index = token offset
        const int c = cg * 64 + (t & 63);
        float ak = 0.f, av = 0.f;
        for (int m = 0; m < DM; ++m) {
            float bm = bank[tok][m];
            ak += bm * Wk[(size_t)m * DM + c];
            av += bm * Wv[(size_t)m * DM + c];
        }
        kb[(size_t)(tg * 8 + tok) * DM + c] = f2bf(ak);
        vtb[(size_t)c * NT + tg * 8 + tok] = f2bf(av);
    } else {
        __shared__ u16 lt[64][65];              // +1 pad breaks write conflicts
        const int tile = b - 128;
        const int k0 = (tile >> 3) * 64, c0 = (tile & 7) * 64;
        const int kr = t >> 3, cc = (t & 7) * 8;
        const float* src = Wq + (size_t)(k0 + kr) * DM + c0 + cc;
        f4_t u0 = *(const f4_t*)src;
        f4_t u1 = *(const f4_t*)(src + 4);
        #pragma unroll
        for (int j = 0; j < 4; ++j) lt[cc + j][kr] = f2bf(u0[j]);
        #pragma unroll
        for (int j = 0; j < 4; ++j) lt[cc + 4 + j][kr] = f2bf(u1[j]);
        __syncthreads();
        const int cr = t >> 3, kk = (t & 7) * 8;
        bf8_t o;
        #pragma unroll
        for (int j = 0; j < 8; ++j) o[j] = (short)lt[cr][kk + j];
        *(bf8_t*)(wqt + (size_t)(c0 + cr) * DQ + k0 + kk) = o;
    }
}

// ---------------------------------------------------------------------------
// fused: grid 2048 (512 row-tiles x 4 head-pairs), 256 threads (4 waves 2x2).
// ---------------------------------------------------------------------------
__global__ __launch_bounds__(256, 3) void fused_kernel(
        const float* __restrict__ z, const u16* __restrict__ wqt,
        const u16* __restrict__ kb, const u16* __restrict__ vtb,
        float* __restrict__ outp, float* __restrict__ scp) {
    __shared__ __align__(16) u16 As[4096];      // [128 m][32 k]
    __shared__ __align__(16) u16 Bs[4096];      // [128 n][32 k]
    __shared__ __align__(16) u16 Pl[4][4096];   // per-wave: q [64][64] / P [16][128]

    // XCD-chunked swizzle: the 4 head-siblings of a row-tile share one XCD L2.
    const int bid = ((blockIdx.x & 7) << 8) | (blockIdx.x >> 3);
    const int m0 = (bid >> 2) * 128;
    const int n0 = (bid & 3) * 128;
    const int tid = threadIdx.x;
    const int w = tid >> 6, l = tid & 63;
    const int wr = w >> 1, wc = w & 1;
    const int ln = l & 15, g = l >> 4;
    const int sr = tid >> 2, sc8 = (tid & 3) * 8;   // staging coords

    // ---- phase 1: q = z @ WqT (K=256, 8 iters, 16 MFMA/iter/wave) ----
    f4_t acc[4][4];
    #pragma unroll
    for (int i = 0; i < 4; ++i)
        #pragma unroll
        for (int j = 0; j < 4; ++j) acc[i][j] = (f4_t){0.f, 0.f, 0.f, 0.f};

    for (int k0 = 0; k0 < DQ; k0 += 32) {
        __syncthreads();
        #pragma unroll
        for (int s = 0; s < 2; ++s) {           // A: f32 -> bf16 reg-staged
            const float* src = z + (size_t)(m0 + s * 64 + sr) * DQ + k0 + sc8;
            f4_t u0 = *(const f4_t*)src;
            f4_t u1 = *(const f4_t*)(src + 4);
            bf8_t o;
            o[0] = (short)f2bf(u0[0]); o[1] = (short)f2bf(u0[1]);
            o[2] = (short)f2bf(u0[2]); o[3] = (short)f2bf(u0[3]);
            o[4] = (short)f2bf(u1[0]); o[5] = (short)f2bf(u1[1]);
            o[6] = (short)f2bf(u1[2]); o[7] = (short)f2bf(u1[3]);
            *(bf8_t*)((char*)As + s * 4096 + tid * 16) = o;
        }
        gload_lds16(wqt + (size_t)(n0 + sr) * DQ + k0 + sc8,      (char*)Bs + w * 1024);
        gload_lds16(wqt + (size_t)(n0 + 64 + sr) * DQ + k0 + sc8, (char*)Bs + 4096 + w * 1024);
        __syncthreads();
        bf8_t a[4], bb[4];
        #pragma unroll
        for (int mi = 0; mi < 4; ++mi)
            a[mi] = *(const bf8_t*)&As[(wr * 64 + mi * 16 + ln) * 32 + g * 8];
        #pragma unroll
        for (int ni = 0; ni < 4; ++ni)
            bb[ni] = *(const bf8_t*)&Bs[(wc * 64 + ni * 16 + ln) * 32 + g * 8];
        #pragma unroll
        for (int mi = 0; mi < 4; ++mi)
            #pragma unroll
            for (int ni = 0; ni < 4; ++ni)
                acc[mi][ni] = __builtin_amdgcn_mfma_f32_16x16x32_bf16(
                    a[mi], bb[ni], acc[mi][ni], 0, 0, 0);
    }

    // ---- phase 2: attention (wave-private; no barriers needed) ----
    const int h = (n0 >> 6) + wc;               // this wave's head
    const int mrow = m0 + wr * 64;              // this wave's first q row
    u16* Pw = Pl[w];

    // q acc (f32, C-layout) -> LDS bf16 [64][64] XOR-swizzled
    #pragma unroll
    for (int mi = 0; mi < 4; ++mi)
        #pragma unroll
        for (int ni = 0; ni < 4; ++ni)
            #pragma unroll
            for (int r = 0; r < 4; ++r) {
                int row = mi * 16 + g * 4 + r;
                int d = ni * 16 + ln;
                Pw[row * 64 + (d ^ ((row & 7) << 3))] =
                    f2bf(acc[mi][ni][r]);
            }
    // q A-frags (same-wave DS ordering guarantees visibility)
    bf8_t qa[4][2];
    #pragma unroll
    for (int mi = 0; mi < 4; ++mi)
        #pragma unroll
        for (int kt = 0; kt < 2; ++kt)
            qa[mi][kt] = *(const bf8_t*)&Pw[(mi * 16 + ln) * 64 +
                            ((kt * 32 + g * 8) ^ ((ln & 7) << 3))];

    #pragma unroll
    for (int mi = 0; mi < 4; ++mi) {
        // QK^T: 16 rows x 128 tokens (K-frags streamed from L1/L2)
        f4_t sc[8];
        #pragma unroll
        for (int tt = 0; tt < 8; ++tt) {
            const u16* kbase = kb + (size_t)(tt * 16 + ln) * DM + h * 64 + g * 8;
            bf8_t kf0 = *(const bf8_t*)kbase;
            bf8_t kf1 = *(const bf8_t*)(kbase + 32);
            f4_t c = (f4_t){0.f, 0.f, 0.f, 0.f};
            c = __builtin_amdgcn_mfma_f32_16x16x32_bf16(qa[mi][0], kf0, c, 0, 0, 0);
            c = __builtin_amdgcn_mfma_f32_16x16x32_bf16(qa[mi][1], kf1, c, 0, 0, 0);
            sc[tt] = c;
        }
        // softmax over 128 tokens: 8 reg-tiles x 16 lanes (shfl over ln bits)
        float mx[4], sum[4], inv[4];
        #pragma unroll
        for (int r = 0; r < 4; ++r) {
            float m = sc[0][r];
            #pragma unroll
            for (int tt = 1; tt < 8; ++tt) m = fmaxf(m, sc[tt][r]);
            #pragma unroll
            for (int msk = 1; msk <= 8; msk <<= 1)
                m = fmaxf(m, __shfl_xor(m, msk));
            mx[r] = m; sum[r] = 0.f;
        }
        #pragma unroll
        for (int tt = 0; tt < 8; ++tt)
            #pragma unroll
            for (int r = 0; r < 4; ++r) {
                float e = __expf((sc[tt][r] - mx[r]) * 0.125f);
                sc[tt][r] = e; sum[r] += e;
            }
        #pragma unroll
        for (int r = 0; r < 4; ++r) {
            float s2 = sum[r];
            #pragma unroll
            for (int msk = 1; msk <= 8; msk <<= 1) s2 += __shfl_xor(s2, msk);
            inv[r] = 1.0f / s2;
        }
        // scores out (f32, streaming) + P slice [16][128] -> LDS (swizzled)
        #pragma unroll
        for (int tt = 0; tt < 8; ++tt)
            #pragma unroll
            for (int r = 0; r < 4; ++r) {
                int rr = g * 4 + r;                    // row within slice
                int tcol = tt * 16 + ln;
                float p = sc[tt][r] * inv[r];
                __builtin_nontemporal_store(p,
                    scp + (size_t)(mrow + mi * 16 + rr) * 1024 + h * 128 + tcol);
                Pw[rr * 128 + (tcol ^ ((rr & 7) << 3))] = f2bf(p);
            }
        // PV: A = P [16][128], B = vT [d][t]
        bf8_t pa[4];
        #pragma unroll
        for (int ks = 0; ks < 4; ++ks)
            pa[ks] = *(const bf8_t*)&Pw[ln * 128 +
                        ((ks * 32 + g * 8) ^ ((ln & 7) << 3))];
        #pragma unroll
        for (int dt = 0; dt < 4; ++dt) {
            f4_t c = (f4_t){0.f, 0.f, 0.f, 0.f};
            #pragma unroll
            for (int ks = 0; ks < 4; ++ks) {
                bf8_t bv = *(const bf8_t*)(vtb +
                    (size_t)(h * 64 + dt * 16 + ln) * NT + ks * 32 + g * 8);
                c = __builtin_amdgcn_mfma_f32_16x16x32_bf16(pa[ks], bv, c, 0, 0, 0);
            }
            #pragma unroll
            for (int r = 0; r < 4; ++r)
                __builtin_nontemporal_store(c[r],
                    outp + (size_t)(mrow + mi * 16 + g * 4 + r) * DM +
                           h * 64 + dt * 16 + ln);
        }
    }
}

// ---------------------------------------------------------------------------
extern "C" void kernel_launch(void* const* d_in, const int* in_sizes, int n_in,
                              void* d_out, int out_size, void* d_ws, size_t ws_size,
                              hipStream_t stream) {
    const float* z     = (const float*)d_in[0];
    const float* embed = (const float*)d_in[1];
    const float* Wq    = (const float*)d_in[2];
    const float* Wk    = (const float*)d_in[3];
    const float* Wv    = (const float*)d_in[4];
    float* outp = (float*)d_out;
    float* scp  = outp + (size_t)65536 * DM;

    u16* ws  = (u16*)d_ws;
    u16* wqt = ws;                  // 131072 elems (256 KB)
    u16* kb  = ws + 131072;         //  65536 elems (128 KB)
    u16* vtb = ws + 196608;         //  65536 elems (128 KB)

    setup_kernel<<<dim3(160), dim3(512), 0, stream>>>(embed, Wq, Wk, Wv, wqt, kb, vtb);
    fused_kernel<<<dim3(2048), dim3(256), 0, stream>>>(z, wqt, kb, vtb, outp, scp);
}